// Round 9
// baseline (913.304 us; speedup 1.0000x reference)
//
#include <hip/hip_runtime.h>
#include <math.h>

#define HEADS1 4
#define HID 64
#define LSTM_H 32
#define IN_F 128
#define T_STEPS 50
#define NEG_SLOPE 0.2f
#define EPS_A 1e-16f

typedef __attribute__((ext_vector_type(8))) short short8;
typedef __attribute__((ext_vector_type(4))) float floatx4;

// ---------- helpers ----------
__device__ __forceinline__ float sigf(float x) { return 1.0f / (1.0f + __expf(-x)); }
__device__ __forceinline__ float tanhfast(float x) {
    float e = __expf(2.0f * x);
    return 1.0f - 2.0f / (e + 1.0f);
}
__device__ __forceinline__ unsigned short f2bf(float f) {
    unsigned u = __float_as_uint(f);
    unsigned r = (u + 0x7FFFu + ((u >> 16) & 1u)) >> 16;
    return (unsigned short)r;
}
__device__ __forceinline__ float bf2f(unsigned short s) {
    return __uint_as_float(((unsigned)s) << 16);
}

// ---------- GEMM: C[M,NC] = A[M,K] @ B[K,NC]; 64x64 tile, 4x4 micro ----------
template <int K, int NC>
__global__ __launch_bounds__(256) void gemm64(const float* __restrict__ A,
                                              const float* __restrict__ B,
                                              float* __restrict__ C, int M) {
    constexpr int KC = 32;
    __shared__ float As[KC][68];
    __shared__ float Bs[KC][64];
    const int row0 = blockIdx.x * 64;
    const int col0 = blockIdx.y * 64;
    const int tx = threadIdx.x & 15;
    const int ty = threadIdx.x >> 4;
    float acc[4][4] = {{0.f}};

    for (int k0 = 0; k0 < K; k0 += KC) {
        {
            const int kk = threadIdx.x & 31;
            const int rb = threadIdx.x >> 5;
#pragma unroll
            for (int r = 0; r < 8; r++) {
                int row = row0 + rb + r * 8;
                As[kk][rb + r * 8] = (row < M) ? A[(size_t)row * K + k0 + kk] : 0.0f;
            }
            const int c  = threadIdx.x & 63;
            const int kb = threadIdx.x >> 6;
#pragma unroll
            for (int q = 0; q < KC / 4; q++)
                Bs[kb + q * 4][c] = B[(size_t)(k0 + kb + q * 4) * NC + col0 + c];
        }
        __syncthreads();
#pragma unroll
        for (int kk = 0; kk < KC; kk++) {
            float4 a4 = *(const float4*)&As[kk][ty * 4];
            float4 b4 = *(const float4*)&Bs[kk][tx * 4];
            float av[4] = {a4.x, a4.y, a4.z, a4.w};
            float bv[4] = {b4.x, b4.y, b4.z, b4.w};
#pragma unroll
            for (int i = 0; i < 4; i++)
#pragma unroll
                for (int j = 0; j < 4; j++) acc[i][j] += av[i] * bv[j];
        }
        __syncthreads();
    }
#pragma unroll
    for (int i = 0; i < 4; i++) {
        int row = row0 + ty * 4 + i;
        if (row < M) {
            float4 v = make_float4(acc[i][0], acc[i][1], acc[i][2], acc[i][3]);
            *(float4*)&C[(size_t)row * NC + col0 + tx * 4] = v;
        }
    }
}

// ---------- attention scores ----------
__global__ void att_scores(const float* __restrict__ h, const float* __restrict__ att_s,
                           const float* __restrict__ att_d, float* __restrict__ as_,
                           float* __restrict__ ad_, int NH, int Hmask) {
    int i = blockIdx.x * blockDim.x + threadIdx.x;
    if (i >= NH) return;
    int hh = i & Hmask;
    const float* row = h + (size_t)i * HID;
    float s = 0.0f, d = 0.0f;
#pragma unroll 8
    for (int c = 0; c < HID; c++) {
        float v = row[c];
        s += v * att_s[hh * HID + c];
        d += v * att_d[hh * HID + c];
    }
    as_[i] = s;
    ad_[i] = d;
}

// ---------- CSR build ----------
__global__ void count_deg(const int* __restrict__ dsts, int E, int ET, int* __restrict__ cnt) {
    int e = blockIdx.x * blockDim.x + threadIdx.x;
    if (e >= ET) return;
    int d = (e < E) ? dsts[e] : (e - E);
    atomicAdd(&cnt[d], 1);
}

__global__ void scan1(const int* __restrict__ cnt, int* __restrict__ rowp,
                      int* __restrict__ bsum, int N) {
    __shared__ int tmp[256];
    int i = blockIdx.x * 256 + threadIdx.x;
    int v = (i < N) ? cnt[i] : 0;
    tmp[threadIdx.x] = v;
    __syncthreads();
    for (int off = 1; off < 256; off <<= 1) {
        int t = (threadIdx.x >= (unsigned)off) ? tmp[threadIdx.x - off] : 0;
        __syncthreads();
        tmp[threadIdx.x] += t;
        __syncthreads();
    }
    if (i < N) rowp[i] = tmp[threadIdx.x] - v;
    if (threadIdx.x == 255) bsum[blockIdx.x] = tmp[255];
}

__global__ void scan2(int* __restrict__ bsum, int nb) {
    __shared__ int tmp[256];
    int v = (threadIdx.x < (unsigned)nb) ? bsum[threadIdx.x] : 0;
    tmp[threadIdx.x] = v;
    __syncthreads();
    for (int off = 1; off < 256; off <<= 1) {
        int t = (threadIdx.x >= (unsigned)off) ? tmp[threadIdx.x - off] : 0;
        __syncthreads();
        tmp[threadIdx.x] += t;
        __syncthreads();
    }
    if (threadIdx.x < (unsigned)nb) bsum[threadIdx.x] = tmp[threadIdx.x] - v;
}

__global__ void scan3(int* __restrict__ rowp, const int* __restrict__ bsum, int N, int ET) {
    int i = blockIdx.x * 256 + threadIdx.x;
    if (i < N) rowp[i] += bsum[blockIdx.x];
    if (i == 0) rowp[N] = ET;
}

__global__ void scatter_edges(const int* __restrict__ dsts, int E, int ET,
                              const int* __restrict__ rowp, int* __restrict__ cursor,
                              int* __restrict__ eid) {
    int e = blockIdx.x * blockDim.x + threadIdx.x;
    if (e >= ET) return;
    int d = (e < E) ? dsts[e] : (e - E);
    int pos = atomicAdd(&cursor[d], 1);
    eid[rowp[d] + pos] = e;
}

// ---------- GAT layer-1 aggregation: single pass, one wave per dst, 4 heads ----------
__global__ __launch_bounds__(256)
void gat_agg4_sp(const int* __restrict__ srcs, int E,
                 const int* __restrict__ rowp, const int* __restrict__ eid,
                 const float* __restrict__ as_, const float* __restrict__ ad_,
                 const float* __restrict__ hfeat, const float* __restrict__ bias,
                 float* __restrict__ g, int N) {
    __shared__ float s_alpha[4][64][4];
    const int wave = threadIdx.x >> 6;
    const int lane = threadIdx.x & 63;
    const int head = lane >> 4;
    const int dst = blockIdx.x * 4 + wave;
    if (dst >= N) return;
    const int start = rowp[dst], end = rowp[dst + 1];
    const float4 adv = ((const float4*)ad_)[dst];
    const float4* h4 = (const float4*)hfeat;

    float4 dsum = make_float4(0.f, 0.f, 0.f, 0.f);
    float4 acc  = make_float4(0.f, 0.f, 0.f, 0.f);

    for (int i0 = start; i0 < end; i0 += 64) {
        int cnt = min(64, end - i0);
        int i = i0 + lane;
        int s = 0;
        if (i < end) {
            int e = eid[i];
            s = (e < E) ? srcs[e] : (e - E);
            float4 a = ((const float4*)as_)[s];
            float tx, ex;
            tx = a.x + adv.x; tx = (tx > 0.f) ? tx : NEG_SLOPE * tx; ex = __expf(tx);
            dsum.x += ex; s_alpha[wave][lane][0] = ex;
            tx = a.y + adv.y; tx = (tx > 0.f) ? tx : NEG_SLOPE * tx; ex = __expf(tx);
            dsum.y += ex; s_alpha[wave][lane][1] = ex;
            tx = a.z + adv.z; tx = (tx > 0.f) ? tx : NEG_SLOPE * tx; ex = __expf(tx);
            dsum.z += ex; s_alpha[wave][lane][2] = ex;
            tx = a.w + adv.w; tx = (tx > 0.f) ? tx : NEG_SLOPE * tx; ex = __expf(tx);
            dsum.w += ex; s_alpha[wave][lane][3] = ex;
        }
        __builtin_amdgcn_wave_barrier();
#pragma unroll 4
        for (int k = 0; k < cnt; k++) {
            float a_k = s_alpha[wave][k][head];
            int   s_k = __shfl(s, k);
            float4 hv = h4[(size_t)s_k * 64 + lane];
            acc.x += a_k * hv.x; acc.y += a_k * hv.y;
            acc.z += a_k * hv.z; acc.w += a_k * hv.w;
        }
        __builtin_amdgcn_wave_barrier();
    }
#pragma unroll
    for (int mk = 32; mk >= 1; mk >>= 1) {
        dsum.x += __shfl_xor(dsum.x, mk);
        dsum.y += __shfl_xor(dsum.y, mk);
        dsum.z += __shfl_xor(dsum.z, mk);
        dsum.w += __shfl_xor(dsum.w, mk);
    }
    float den = (head == 0) ? dsum.x : (head == 1) ? dsum.y : (head == 2) ? dsum.z : dsum.w;
    float inv = 1.0f / (den + EPS_A);
    float4 b4 = ((const float4*)bias)[lane];
    float4 r;
    r.x = acc.x * inv + b4.x; r.x = (r.x > 0.f) ? r.x : __expf(r.x) - 1.f;
    r.y = acc.y * inv + b4.y; r.y = (r.y > 0.f) ? r.y : __expf(r.y) - 1.f;
    r.z = acc.z * inv + b4.z; r.z = (r.z > 0.f) ? r.z : __expf(r.z) - 1.f;
    r.w = acc.w * inv + b4.w; r.w = (r.w > 0.f) ? r.w : __expf(r.w) - 1.f;
    ((float4*)g)[(size_t)dst * 64 + lane] = r;
}

// ---------- GAT layer-2 aggregation: single pass, one wave per dst, H=1 ----------
__global__ __launch_bounds__(256)
void gat_agg1_sp(const int* __restrict__ srcs, int E,
                 const int* __restrict__ rowp, const int* __restrict__ eid,
                 const float* __restrict__ as_, const float* __restrict__ ad_,
                 const float* __restrict__ hfeat, const float* __restrict__ bias,
                 float* __restrict__ g, int N) {
    __shared__ float s_alpha[4][64];
    const int wave = threadIdx.x >> 6;
    const int lane = threadIdx.x & 63;
    const int dst = blockIdx.x * 4 + wave;
    if (dst >= N) return;
    const int start = rowp[dst], end = rowp[dst + 1];
    const float adv = ad_[dst];

    float dsum = 0.0f, acc = 0.0f;
    for (int i0 = start; i0 < end; i0 += 64) {
        int cnt = min(64, end - i0);
        int i = i0 + lane;
        int s = 0;
        if (i < end) {
            int e = eid[i];
            s = (e < E) ? srcs[e] : (e - E);
            float t = as_[s] + adv;
            t = (t > 0.f) ? t : NEG_SLOPE * t;
            float ex = __expf(t);
            dsum += ex;
            s_alpha[wave][lane] = ex;
        }
        __builtin_amdgcn_wave_barrier();
#pragma unroll 4
        for (int k = 0; k < cnt; k++) {
            float a_k = s_alpha[wave][k];
            int   s_k = __shfl(s, k);
            acc += a_k * hfeat[(size_t)s_k * 64 + lane];
        }
        __builtin_amdgcn_wave_barrier();
    }
#pragma unroll
    for (int mk = 32; mk >= 1; mk >>= 1) dsum += __shfl_xor(dsum, mk);
    g[(size_t)dst * 64 + lane] = acc / (dsum + EPS_A) + bias[lane];
}

// ---------- LSTM via MFMA (split-bf16), round-9: units split across 2 waves ----------
// Block = 4 waves = 2 node-groups x 2 parity-waves; wave parity p owns units
// p*16..p*16+15 (gate-blocks {p,2+p,4+p,6+p}): 16 MFMAs + 4 unit-nonlinearities
// per lane-ts (half of r8). h exchanged via double-buffered s_h with ONE
// __syncthreads per ts. Grid doubles to N/32 blocks.
__global__ __launch_bounds__(256, 4)
void lstm_mfma(const float* __restrict__ seq, const float* __restrict__ Wih,
               const float* __restrict__ Whh, const float* __restrict__ bih,
               const float* __restrict__ bhh, float* __restrict__ t_out, int N) {
    __shared__ unsigned short sWhi[4096];   // lane-order swizzled (8 KB)
    __shared__ unsigned short sWlo[4096];
    __shared__ unsigned short sB2[4096];
    __shared__ float s_h[2][2][16][36];     // [buf][group][node][unit] 9.2 KB

    const int tid  = threadIdx.x;
    const int wave = tid >> 6, lane = tid & 63;
    const int grp  = lane >> 4, col = lane & 15;
    const int g    = wave >> 1;     // node group within block
    const int p    = wave & 1;      // unit-parity: units p*16+col
    const int node0 = blockIdx.x * 32 + g * 16;

    // ---- stage Whh hi/lo, swizzled: slot i=(b*64+L)*8+j holds W[n=b*16+(L&15)][k=(L>>4)*8+j]
    for (int i = tid; i < 4096; i += 256) {
        int j = i & 7, L = (i >> 3) & 63, b = i >> 9;
        int n = b * 16 + (L & 15);
        int k = (L >> 4) * 8 + j;
        float v = Whh[n * 32 + k];
        unsigned short hi = f2bf(v);
        sWhi[i] = hi;
        sWlo[i] = f2bf(v - bf2f(hi));
    }
    // ---- stage B2 (x-path), same swizzle ----
    for (int i = tid; i < 4096; i += 256) {
        int j = i & 7, L = (i >> 3) & 63, b = i >> 9;
        int n = b * 16 + (L & 15);
        int k = (L >> 4) * 8 + j;
        unsigned short val = 0;
        if (k < 3) {
            val = f2bf(Wih[n * 3 + k]);
        } else if (k == 3) {
            val = f2bf(bih[n] + bhh[n]);
        } else if (k < 7) {
            val = f2bf(Wih[n * 3 + (k - 4)]);
        } else if (k == 7) {
            float bb = bih[n] + bhh[n];
            val = f2bf(bb - bf2f(f2bf(bb)));
        } else if (k < 11) {
            float wv = Wih[n * 3 + (k - 8)];
            val = f2bf(wv - bf2f(f2bf(wv)));
        }
        sB2[i] = val;
    }
    for (int i = tid; i < 2 * 2 * 16 * 36; i += 256) ((float*)s_h)[i] = 0.0f;
    __syncthreads();

    float cst[4] = {0.f, 0.f, 0.f, 0.f};
    float hnew[4] = {0.f, 0.f, 0.f, 0.f};
    const floatx4 zac = {0.f, 0.f, 0.f, 0.f};

    const int nodeX = node0 + col;
    const bool vx = (nodeX < N) && (grp < 2);
    const float* xp = seq + (size_t)nodeX * (T_STEPS * 3);

#pragma unroll 1
    for (int t = 0; t < T_STEPS; t++) {
        const int cur = t & 1, nxt = cur ^ 1;
        // ---- A2: x hi/lo + ones in K-slots (grp0: k'0-7, grp1: k'8-10) ----
        float xv0 = vx ? xp[t * 3 + 0] : 0.0f;
        float xv1 = vx ? xp[t * 3 + 1] : 0.0f;
        float xv2 = vx ? xp[t * 3 + 2] : 0.0f;
        unsigned short xh0 = f2bf(xv0), xh1 = f2bf(xv1), xh2 = f2bf(xv2);
        unsigned short xl0 = f2bf(xv0 - bf2f(xh0));
        unsigned short xl1 = f2bf(xv1 - bf2f(xh1));
        unsigned short xl2 = f2bf(xv2 - bf2f(xh2));
        const short oneb = (short)0x3F80;
        bool g0 = (grp == 0);
        short8 A2;
        A2[0] = (short)xh0; A2[1] = (short)xh1; A2[2] = (short)xh2;
        A2[3] = g0 ? oneb : (short)0;
        A2[4] = g0 ? (short)xl0 : (short)0;
        A2[5] = g0 ? (short)xl1 : (short)0;
        A2[6] = g0 ? (short)xl2 : (short)0;
        A2[7] = g0 ? oneb : (short)0;

        // ---- A (h) hi/lo from LDS (full K=32: both parities' units) ----
        const float* hr = &s_h[cur][g][col][grp * 8];
        floatx4 h0 = *(const floatx4*)&hr[0];
        floatx4 h1 = *(const floatx4*)&hr[4];
        float hv[8] = {h0[0], h0[1], h0[2], h0[3], h1[0], h1[1], h1[2], h1[3]};
        short8 Ahi, Alo;
#pragma unroll
        for (int j = 0; j < 8; j++) {
            unsigned short hi = f2bf(hv[j]);
            Ahi[j] = (short)hi;
            Alo[j] = (short)f2bf(hv[j] - bf2f(hi));
        }

        // ---- this wave's 4 gate-blocks {p,2+p,4+p,6+p} x 4 MFMAs ----
        floatx4 acc[4];
#pragma unroll
        for (int gb = 0; gb < 4; gb++) {
            const int b = gb * 2 + p;
            short8 B2f = *(const short8*)&sB2[(b * 64 + lane) * 8];
            short8 Bhi = *(const short8*)&sWhi[(b * 64 + lane) * 8];
            short8 Blo = *(const short8*)&sWlo[(b * 64 + lane) * 8];
            floatx4 d = __builtin_amdgcn_mfma_f32_16x16x32_bf16(A2, B2f, zac, 0, 0, 0);
            d = __builtin_amdgcn_mfma_f32_16x16x32_bf16(Alo, Bhi, d, 0, 0, 0);
            d = __builtin_amdgcn_mfma_f32_16x16x32_bf16(Ahi, Blo, d, 0, 0, 0);
            acc[gb] = __builtin_amdgcn_mfma_f32_16x16x32_bf16(Ahi, Bhi, d, 0, 0, 0);
        }

        // ---- gates: lane owns unit p*16+col of 4 nodes ----
#pragma unroll
        for (int q = 0; q < 4; q++) {
            float zi = acc[0][q], zf = acc[1][q], zg = acc[2][q], zo = acc[3][q];
            float ig = sigf(zi), fg = sigf(zf);
            float gv = tanhfast(zg), og = sigf(zo);
            cst[q] = fg * cst[q] + ig * gv;
            hnew[q] = og * tanhfast(cst[q]);
        }

        // ---- h writeback into the OTHER buffer; one barrier per ts ----
#pragma unroll
        for (int q = 0; q < 4; q++)
            s_h[nxt][g][4 * grp + q][p * 16 + col] = hnew[q];
        __syncthreads();
    }

#pragma unroll
    for (int q = 0; q < 4; q++) {
        int node = node0 + 4 * grp + q;
        if (node < N) t_out[(size_t)node * LSTM_H + p * 16 + col] = hnew[q];
    }
}

// ---------- fusion MLP ----------
__global__ void fusion_kernel(const float* __restrict__ g2, const float* __restrict__ tt,
                              const float* __restrict__ Wf1, const float* __restrict__ bf1,
                              const float* __restrict__ Wf2, const float* __restrict__ bf2,
                              float* __restrict__ out, int N) {
    __shared__ float sW[96 * 64];
    __shared__ float sb1[64];
    __shared__ float sW2[128];
    for (int i = threadIdx.x; i < 96 * 64; i += 256) sW[i] = Wf1[i];
    if (threadIdx.x < 64) sb1[threadIdx.x] = bf1[threadIdx.x];
    if (threadIdx.x < 128) sW2[threadIdx.x] = Wf2[threadIdx.x];
    __syncthreads();
    const int wave = threadIdx.x >> 6;
    const int lane = threadIdx.x & 63;
    for (int n = blockIdx.x * 4 + wave; n < N; n += gridDim.x * 4) {
        const float* gn = g2 + (size_t)n * 64;
        const float* tn = tt + (size_t)n * 32;
        float acc = sb1[lane];
#pragma unroll 8
        for (int k = 0; k < 64; k++) acc += gn[k] * sW[k * 64 + lane];
#pragma unroll 8
        for (int k = 0; k < 32; k++) acc += tn[k] * sW[(64 + k) * 64 + lane];
        acc = fmaxf(acc, 0.0f);
        float o0 = acc * sW2[lane * 2 + 0];
        float o1 = acc * sW2[lane * 2 + 1];
#pragma unroll
        for (int mk = 32; mk >= 1; mk >>= 1) {
            o0 += __shfl_xor(o0, mk);
            o1 += __shfl_xor(o1, mk);
        }
        if (lane == 0) {
            out[(size_t)n * 2 + 0] = o0 + bf2[0];
            out[(size_t)n * 2 + 1] = o1 + bf2[1];
        }
    }
}

extern "C" void kernel_launch(void* const* d_in, const int* in_sizes, int n_in,
                              void* d_out, int out_size, void* d_ws, size_t ws_size,
                              hipStream_t stream) {
    const float* x      = (const float*)d_in[0];
    const int*   eidx   = (const int*)d_in[1];
    const float* seq    = (const float*)d_in[2];
    const float* W1     = (const float*)d_in[3];
    const float* att_s1 = (const float*)d_in[4];
    const float* att_d1 = (const float*)d_in[5];
    const float* bias1  = (const float*)d_in[6];
    const float* W2     = (const float*)d_in[7];
    const float* att_s2 = (const float*)d_in[8];
    const float* att_d2 = (const float*)d_in[9];
    const float* bias2  = (const float*)d_in[10];
    const float* Wih    = (const float*)d_in[11];
    const float* Whh    = (const float*)d_in[12];
    const float* bih    = (const float*)d_in[13];
    const float* bhh    = (const float*)d_in[14];
    const float* Wf1    = (const float*)d_in[15];
    const float* bf1    = (const float*)d_in[16];
    const float* Wf2    = (const float*)d_in[17];
    const float* bf2    = (const float*)d_in[18];
    float* out = (float*)d_out;

    const int N  = in_sizes[0] / IN_F;   // 50000
    const int E  = in_sizes[1] / 2;      // 800000
    const int ET = E + N;
    const int* srcs = eidx;
    const int* dsts = eidx + E;

    // workspace layout
    float* fws = (float*)d_ws;
    size_t o = 0;
    float* h1  = fws + o; o += (size_t)N * 256;
    float* g1  = fws + o; o += (size_t)N * 256;
    float* as1 = fws + o; o += (size_t)N * 4;
    float* ad1 = fws + o; o += (size_t)N * 4;
    int* cnt    = (int*)(fws + o);
    int* rowp   = cnt + N;
    int* cursor = rowp + N + 1;
    int* eid    = cursor + N;
    int* bsum   = eid + ET;
    // layer-2 / LSTM aliases (h1 region dead after layer-1 aggregation)
    float* h2 = h1;                      // N*64
    float* g2 = h1 + (size_t)N * 64;     // N*64
    float* tt = h1 + (size_t)N * 128;    // N*32
    float* as2 = as1; float* ad2 = ad1;

    const int nTiles = (N + 255) / 256;
    dim3 blk(256);

    // ---- CSR build ----
    hipMemsetAsync(cnt, 0, (size_t)N * sizeof(int), stream);
    hipMemsetAsync(cursor, 0, (size_t)N * sizeof(int), stream);
    count_deg<<<(ET + 255) / 256, blk, 0, stream>>>(dsts, E, ET, cnt);
    scan1<<<nTiles, blk, 0, stream>>>(cnt, rowp, bsum, N);
    scan2<<<1, blk, 0, stream>>>(bsum, nTiles);
    scan3<<<(N + 256) / 256, blk, 0, stream>>>(rowp, bsum, N, ET);
    scatter_edges<<<(ET + 255) / 256, blk, 0, stream>>>(dsts, E, ET, rowp, cursor, eid);

    // ---- GAT layer 1 ----
    gemm64<128, 256><<<dim3((N + 63) / 64, 4), blk, 0, stream>>>(x, W1, h1, N);
    att_scores<<<(N * 4 + 255) / 256, blk, 0, stream>>>(h1, att_s1, att_d1, as1, ad1, N * 4, 3);
    gat_agg4_sp<<<(N + 3) / 4, blk, 0, stream>>>(srcs, E, rowp, eid, as1, ad1, h1, bias1, g1, N);

    // ---- LSTM (MFMA; tt region free once layer-1 agg is done) ----
    lstm_mfma<<<(N + 31) / 32, blk, 0, stream>>>(seq, Wih, Whh, bih, bhh, tt, N);

    // ---- GAT layer 2 ----
    gemm64<256, 64><<<dim3((N + 63) / 64, 1), blk, 0, stream>>>(g1, W2, h2, N);
    att_scores<<<(N + 255) / 256, blk, 0, stream>>>(h2, att_s2, att_d2, as2, ad2, N, 0);
    gat_agg1_sp<<<(N + 3) / 4, blk, 0, stream>>>(srcs, E, rowp, eid, as2, ad2, h2, bias2, g2, N);

    // ---- fusion MLP ----
    fusion_kernel<<<512, blk, 0, stream>>>(g2, tt, Wf1, bf1, Wf2, bf2, out, N);
}

// Round 11
// 904.447 us; speedup vs baseline: 1.0098x; 1.0098x over previous
//
#include <hip/hip_runtime.h>
#include <math.h>

#define HEADS1 4
#define HID 64
#define LSTM_H 32
#define IN_F 128
#define T_STEPS 50
#define NEG_SLOPE 0.2f
#define EPS_A 1e-16f

typedef __attribute__((ext_vector_type(8))) short short8;
typedef __attribute__((ext_vector_type(4))) float floatx4;

// ---------- helpers ----------
__device__ __forceinline__ float sigf(float x) { return 1.0f / (1.0f + __expf(-x)); }
__device__ __forceinline__ float tanhfast(float x) {
    float e = __expf(2.0f * x);
    return 1.0f - 2.0f / (e + 1.0f);
}
__device__ __forceinline__ unsigned short f2bf(float f) {
    unsigned u = __float_as_uint(f);
    unsigned r = (u + 0x7FFFu + ((u >> 16) & 1u)) >> 16;
    return (unsigned short)r;
}
__device__ __forceinline__ float bf2f(unsigned short s) {
    return __uint_as_float(((unsigned)s) << 16);
}

// ---------- GEMM + fused attention scores ----------
// blockIdx.y's 64-col slab == head; epilogue reduces per-row dots with
// att_src/att_dst across the 16 tx lanes (shfl_xor<16, same wave).
template <int K, int NC, int H>
__global__ __launch_bounds__(256) void gemm64(const float* __restrict__ A,
                                              const float* __restrict__ B,
                                              float* __restrict__ C, int M,
                                              const float* __restrict__ att_s,
                                              const float* __restrict__ att_d,
                                              float* __restrict__ as_,
                                              float* __restrict__ ad_) {
    constexpr int KC = 32;
    __shared__ float As[KC][68];
    __shared__ float Bs[KC][64];
    const int row0 = blockIdx.x * 64;
    const int col0 = blockIdx.y * 64;
    const int tx = threadIdx.x & 15;
    const int ty = threadIdx.x >> 4;
    float acc[4][4] = {{0.f}};

    for (int k0 = 0; k0 < K; k0 += KC) {
        {
            const int kk = threadIdx.x & 31;
            const int rb = threadIdx.x >> 5;
#pragma unroll
            for (int r = 0; r < 8; r++) {
                int row = row0 + rb + r * 8;
                As[kk][rb + r * 8] = (row < M) ? A[(size_t)row * K + k0 + kk] : 0.0f;
            }
            const int c  = threadIdx.x & 63;
            const int kb = threadIdx.x >> 6;
#pragma unroll
            for (int q = 0; q < KC / 4; q++)
                Bs[kb + q * 4][c] = B[(size_t)(k0 + kb + q * 4) * NC + col0 + c];
        }
        __syncthreads();
#pragma unroll
        for (int kk = 0; kk < KC; kk++) {
            float4 a4 = *(const float4*)&As[kk][ty * 4];
            float4 b4 = *(const float4*)&Bs[kk][tx * 4];
            float av[4] = {a4.x, a4.y, a4.z, a4.w};
            float bv[4] = {b4.x, b4.y, b4.z, b4.w};
#pragma unroll
            for (int i = 0; i < 4; i++)
#pragma unroll
                for (int j = 0; j < 4; j++) acc[i][j] += av[i] * bv[j];
        }
        __syncthreads();
    }
#pragma unroll
    for (int i = 0; i < 4; i++) {
        int row = row0 + ty * 4 + i;
        if (row < M) {
            float4 v = make_float4(acc[i][0], acc[i][1], acc[i][2], acc[i][3]);
            *(float4*)&C[(size_t)row * NC + col0 + tx * 4] = v;
        }
    }
    // ---- fused attention scores ----
    const int head = (H == 4) ? blockIdx.y : 0;
    float4 asv = *(const float4*)&att_s[head * 64 + tx * 4];
    float4 adv = *(const float4*)&att_d[head * 64 + tx * 4];
#pragma unroll
    for (int i = 0; i < 4; i++) {
        float ps = acc[i][0] * asv.x + acc[i][1] * asv.y + acc[i][2] * asv.z + acc[i][3] * asv.w;
        float pd = acc[i][0] * adv.x + acc[i][1] * adv.y + acc[i][2] * adv.z + acc[i][3] * adv.w;
#pragma unroll
        for (int mk = 8; mk >= 1; mk >>= 1) {
            ps += __shfl_xor(ps, mk);
            pd += __shfl_xor(pd, mk);
        }
        int row = row0 + ty * 4 + i;
        if (tx == 0 && row < M) {
            as_[row * H + head] = ps;
            ad_[row * H + head] = pd;
        }
    }
}

// ---------- CSR build ----------
__global__ void count_deg(const int* __restrict__ dsts, int E, int ET, int* __restrict__ cnt) {
    int e = blockIdx.x * blockDim.x + threadIdx.x;
    if (e >= ET) return;
    int d = (e < E) ? dsts[e] : (e - E);
    atomicAdd(&cnt[d], 1);
}

__global__ void scan1(const int* __restrict__ cnt, int* __restrict__ rowp,
                      int* __restrict__ bsum, int N) {
    __shared__ int tmp[256];
    int i = blockIdx.x * 256 + threadIdx.x;
    int v = (i < N) ? cnt[i] : 0;
    tmp[threadIdx.x] = v;
    __syncthreads();
    for (int off = 1; off < 256; off <<= 1) {
        int t = (threadIdx.x >= (unsigned)off) ? tmp[threadIdx.x - off] : 0;
        __syncthreads();
        tmp[threadIdx.x] += t;
        __syncthreads();
    }
    if (i < N) rowp[i] = tmp[threadIdx.x] - v;
    if (threadIdx.x == 255) bsum[blockIdx.x] = tmp[255];
}

__global__ void scan2(int* __restrict__ bsum, int nb) {
    __shared__ int tmp[256];
    int v = (threadIdx.x < (unsigned)nb) ? bsum[threadIdx.x] : 0;
    tmp[threadIdx.x] = v;
    __syncthreads();
    for (int off = 1; off < 256; off <<= 1) {
        int t = (threadIdx.x >= (unsigned)off) ? tmp[threadIdx.x - off] : 0;
        __syncthreads();
        tmp[threadIdx.x] += t;
        __syncthreads();
    }
    if (threadIdx.x < (unsigned)nb) bsum[threadIdx.x] = tmp[threadIdx.x] - v;
}

__global__ void scan3(int* __restrict__ rowp, const int* __restrict__ bsum, int N, int ET) {
    int i = blockIdx.x * 256 + threadIdx.x;
    if (i < N) rowp[i] += bsum[blockIdx.x];
    if (i == 0) rowp[N] = ET;
}

__global__ void scatter_edges(const int* __restrict__ dsts, int E, int ET,
                              const int* __restrict__ rowp, int* __restrict__ cursor,
                              int* __restrict__ eid) {
    int e = blockIdx.x * blockDim.x + threadIdx.x;
    if (e >= ET) return;
    int d = (e < E) ? dsts[e] : (e - E);
    int pos = atomicAdd(&cursor[d], 1);
    eid[rowp[d] + pos] = e;
}

// ================= mega kernel bodies =================
#define SMEM_BYTES 33792

// ---------- LSTM body (identical math to round 9) ----------
__device__ __forceinline__ void lstm_body(char* smem,
                                          const float* __restrict__ seq,
                                          const float* __restrict__ Wih,
                                          const float* __restrict__ Whh,
                                          const float* __restrict__ bih,
                                          const float* __restrict__ bhh,
                                          float* __restrict__ t_out, int N, int bid) {
    unsigned short* sWhi = (unsigned short*)smem;          // 8 KB
    unsigned short* sWlo = sWhi + 4096;                    // 8 KB
    unsigned short* sB2  = sWlo + 4096;                    // 8 KB
    float (*s_h)[2][16][36] = (float(*)[2][16][36])(smem + 24576);  // 9.2 KB

    const int tid  = threadIdx.x;
    const int wave = tid >> 6, lane = tid & 63;
    const int grp  = lane >> 4, col = lane & 15;
    const int g    = wave >> 1;
    const int p    = wave & 1;
    const int node0 = bid * 32 + g * 16;

    for (int i = tid; i < 4096; i += 256) {
        int j = i & 7, L = (i >> 3) & 63, b = i >> 9;
        int n = b * 16 + (L & 15);
        int k = (L >> 4) * 8 + j;
        float v = Whh[n * 32 + k];
        unsigned short hi = f2bf(v);
        sWhi[i] = hi;
        sWlo[i] = f2bf(v - bf2f(hi));
    }
    for (int i = tid; i < 4096; i += 256) {
        int j = i & 7, L = (i >> 3) & 63, b = i >> 9;
        int n = b * 16 + (L & 15);
        int k = (L >> 4) * 8 + j;
        unsigned short val = 0;
        if (k < 3) {
            val = f2bf(Wih[n * 3 + k]);
        } else if (k == 3) {
            val = f2bf(bih[n] + bhh[n]);
        } else if (k < 7) {
            val = f2bf(Wih[n * 3 + (k - 4)]);
        } else if (k == 7) {
            float bb = bih[n] + bhh[n];
            val = f2bf(bb - bf2f(f2bf(bb)));
        } else if (k < 11) {
            float wv = Wih[n * 3 + (k - 8)];
            val = f2bf(wv - bf2f(f2bf(wv)));
        }
        sB2[i] = val;
    }
    for (int i = tid; i < 2 * 2 * 16 * 36; i += 256) ((float*)s_h)[i] = 0.0f;
    __syncthreads();

    float cst[4] = {0.f, 0.f, 0.f, 0.f};
    float hnew[4] = {0.f, 0.f, 0.f, 0.f};
    const floatx4 zac = {0.f, 0.f, 0.f, 0.f};

    const int nodeX = node0 + col;
    const bool vx = (nodeX < N) && (grp < 2);
    const float* xp = seq + (size_t)nodeX * (T_STEPS * 3);

#pragma unroll 1
    for (int t = 0; t < T_STEPS; t++) {
        const int cur = t & 1, nxt = cur ^ 1;
        float xv0 = vx ? xp[t * 3 + 0] : 0.0f;
        float xv1 = vx ? xp[t * 3 + 1] : 0.0f;
        float xv2 = vx ? xp[t * 3 + 2] : 0.0f;
        unsigned short xh0 = f2bf(xv0), xh1 = f2bf(xv1), xh2 = f2bf(xv2);
        unsigned short xl0 = f2bf(xv0 - bf2f(xh0));
        unsigned short xl1 = f2bf(xv1 - bf2f(xh1));
        unsigned short xl2 = f2bf(xv2 - bf2f(xh2));
        const short oneb = (short)0x3F80;
        bool g0 = (grp == 0);
        short8 A2;
        A2[0] = (short)xh0; A2[1] = (short)xh1; A2[2] = (short)xh2;
        A2[3] = g0 ? oneb : (short)0;
        A2[4] = g0 ? (short)xl0 : (short)0;
        A2[5] = g0 ? (short)xl1 : (short)0;
        A2[6] = g0 ? (short)xl2 : (short)0;
        A2[7] = g0 ? oneb : (short)0;

        const float* hrow = &s_h[cur][g][col][grp * 8];
        floatx4 h0 = *(const floatx4*)&hrow[0];
        floatx4 h1 = *(const floatx4*)&hrow[4];
        float hv[8] = {h0[0], h0[1], h0[2], h0[3], h1[0], h1[1], h1[2], h1[3]};
        short8 Ahi, Alo;
#pragma unroll
        for (int j = 0; j < 8; j++) {
            unsigned short hi = f2bf(hv[j]);
            Ahi[j] = (short)hi;
            Alo[j] = (short)f2bf(hv[j] - bf2f(hi));
        }

        floatx4 acc[4];
#pragma unroll
        for (int gb = 0; gb < 4; gb++) {
            const int b = gb * 2 + p;
            short8 B2f = *(const short8*)&sB2[(b * 64 + lane) * 8];
            short8 Bhi = *(const short8*)&sWhi[(b * 64 + lane) * 8];
            short8 Blo = *(const short8*)&sWlo[(b * 64 + lane) * 8];
            floatx4 d = __builtin_amdgcn_mfma_f32_16x16x32_bf16(A2, B2f, zac, 0, 0, 0);
            d = __builtin_amdgcn_mfma_f32_16x16x32_bf16(Alo, Bhi, d, 0, 0, 0);
            d = __builtin_amdgcn_mfma_f32_16x16x32_bf16(Ahi, Blo, d, 0, 0, 0);
            acc[gb] = __builtin_amdgcn_mfma_f32_16x16x32_bf16(Ahi, Bhi, d, 0, 0, 0);
        }

#pragma unroll
        for (int q = 0; q < 4; q++) {
            float zi = acc[0][q], zf = acc[1][q], zg = acc[2][q], zo = acc[3][q];
            float ig = sigf(zi), fg = sigf(zf);
            float gv = tanhfast(zg), og = sigf(zo);
            cst[q] = fg * cst[q] + ig * gv;
            hnew[q] = og * tanhfast(cst[q]);
        }

#pragma unroll
        for (int q = 0; q < 4; q++)
            s_h[nxt][g][4 * grp + q][p * 16 + col] = hnew[q];
        __syncthreads();
    }

#pragma unroll
    for (int q = 0; q < 4; q++) {
        int node = node0 + 4 * grp + q;
        if (node < N) t_out[(size_t)node * LSTM_H + p * 16 + col] = hnew[q];
    }
}

// ---------- agg4 body (identical math to round 8) ----------
__device__ __forceinline__ void agg4_body(char* smem,
                                          const int* __restrict__ srcs, int E,
                                          const int* __restrict__ rowp,
                                          const int* __restrict__ eid,
                                          const float* __restrict__ as_,
                                          const float* __restrict__ ad_,
                                          const float* __restrict__ hfeat,
                                          const float* __restrict__ bias,
                                          float* __restrict__ g, int N, int bid) {
    float (*s_alpha)[64][4] = (float(*)[64][4])smem;   // 4 KB
    const int wave = threadIdx.x >> 6;
    const int lane = threadIdx.x & 63;
    const int head = lane >> 4;
    const int dst = bid * 4 + wave;
    if (dst >= N) return;
    const int start = rowp[dst], end = rowp[dst + 1];
    const float4 adv = ((const float4*)ad_)[dst];
    const float4* h4 = (const float4*)hfeat;

    float4 dsum = make_float4(0.f, 0.f, 0.f, 0.f);
    float4 acc  = make_float4(0.f, 0.f, 0.f, 0.f);

    for (int i0 = start; i0 < end; i0 += 64) {
        int cnt = min(64, end - i0);
        int i = i0 + lane;
        int s = 0;
        if (i < end) {
            int e = eid[i];
            s = (e < E) ? srcs[e] : (e - E);
            float4 a = ((const float4*)as_)[s];
            float tx, ex;
            tx = a.x + adv.x; tx = (tx > 0.f) ? tx : NEG_SLOPE * tx; ex = __expf(tx);
            dsum.x += ex; s_alpha[wave][lane][0] = ex;
            tx = a.y + adv.y; tx = (tx > 0.f) ? tx : NEG_SLOPE * tx; ex = __expf(tx);
            dsum.y += ex; s_alpha[wave][lane][1] = ex;
            tx = a.z + adv.z; tx = (tx > 0.f) ? tx : NEG_SLOPE * tx; ex = __expf(tx);
            dsum.z += ex; s_alpha[wave][lane][2] = ex;
            tx = a.w + adv.w; tx = (tx > 0.f) ? tx : NEG_SLOPE * tx; ex = __expf(tx);
            dsum.w += ex; s_alpha[wave][lane][3] = ex;
        }
        __builtin_amdgcn_wave_barrier();
#pragma unroll 4
        for (int k = 0; k < cnt; k++) {
            float a_k = s_alpha[wave][k][head];
            int   s_k = __shfl(s, k);
            float4 hv = h4[(size_t)s_k * 64 + lane];
            acc.x += a_k * hv.x; acc.y += a_k * hv.y;
            acc.z += a_k * hv.z; acc.w += a_k * hv.w;
        }
        __builtin_amdgcn_wave_barrier();
    }
#pragma unroll
    for (int mk = 32; mk >= 1; mk >>= 1) {
        dsum.x += __shfl_xor(dsum.x, mk);
        dsum.y += __shfl_xor(dsum.y, mk);
        dsum.z += __shfl_xor(dsum.z, mk);
        dsum.w += __shfl_xor(dsum.w, mk);
    }
    float den = (head == 0) ? dsum.x : (head == 1) ? dsum.y : (head == 2) ? dsum.z : dsum.w;
    float inv = 1.0f / (den + EPS_A);
    float4 b4 = ((const float4*)bias)[lane];
    float4 r;
    r.x = acc.x * inv + b4.x; r.x = (r.x > 0.f) ? r.x : __expf(r.x) - 1.f;
    r.y = acc.y * inv + b4.y; r.y = (r.y > 0.f) ? r.y : __expf(r.y) - 1.f;
    r.z = acc.z * inv + b4.z; r.z = (r.z > 0.f) ? r.z : __expf(r.z) - 1.f;
    r.w = acc.w * inv + b4.w; r.w = (r.w > 0.f) ? r.w : __expf(r.w) - 1.f;
    ((float4*)g)[(size_t)dst * 64 + lane] = r;
}

// ---------- mega: interleaved LSTM + agg4 (bid%9==0 -> LSTM) ----------
__global__ __launch_bounds__(256, 4)
void mega_agg4_lstm(const int* __restrict__ srcs, int E,
                    const int* __restrict__ rowp, const int* __restrict__ eid,
                    const float* __restrict__ as_, const float* __restrict__ ad_,
                    const float* __restrict__ hfeat, const float* __restrict__ bias,
                    float* __restrict__ g, int N,
                    const float* __restrict__ seq, const float* __restrict__ Wih,
                    const float* __restrict__ Whh, const float* __restrict__ bih,
                    const float* __restrict__ bhh, float* __restrict__ t_out,
                    int lstmBlocks) {
    __shared__ __align__(16) char smem[SMEM_BYTES];
    const int bid = blockIdx.x;
    const int q = bid / 9, r = bid - q * 9;
    if (lstmBlocks > 0 && r == 0 && q < lstmBlocks) {
        lstm_body(smem, seq, Wih, Whh, bih, bhh, t_out, N, q);
        return;
    }
    const int aggIdx = bid - min(q + 1, lstmBlocks);
    agg4_body(smem, srcs, E, rowp, eid, as_, ad_, hfeat, bias, g, N, aggIdx);
}

// standalone LSTM (fallback when workspace can't host a dedicated tt)
__global__ __launch_bounds__(256, 4)
void lstm_standalone(const float* __restrict__ seq, const float* __restrict__ Wih,
                     const float* __restrict__ Whh, const float* __restrict__ bih,
                     const float* __restrict__ bhh, float* __restrict__ t_out, int N) {
    __shared__ __align__(16) char smem[SMEM_BYTES];
    lstm_body(smem, seq, Wih, Whh, bih, bhh, t_out, N, blockIdx.x);
}

// ---------- agg1 + fusion MLP fused: wave per dst, grid-stride ----------
__global__ __launch_bounds__(256)
void gat_agg1_fused(const int* __restrict__ srcs, int E,
                    const int* __restrict__ rowp, const int* __restrict__ eid,
                    const float* __restrict__ as_, const float* __restrict__ ad_,
                    const float* __restrict__ hfeat, const float* __restrict__ bias2,
                    const float* __restrict__ tt,
                    const float* __restrict__ Wf1, const float* __restrict__ bf1,
                    const float* __restrict__ Wf2, const float* __restrict__ bf2,
                    float* __restrict__ out, int N) {
    __shared__ float sW[96 * 64];
    __shared__ float sb1[64];
    __shared__ float sW2[128];
    __shared__ float s_alpha[4][64];
    for (int i = threadIdx.x; i < 96 * 64; i += 256) sW[i] = Wf1[i];
    if (threadIdx.x < 64) sb1[threadIdx.x] = bf1[threadIdx.x];
    if (threadIdx.x < 128) sW2[threadIdx.x] = Wf2[threadIdx.x];
    __syncthreads();
    const int wave = threadIdx.x >> 6;
    const int lane = threadIdx.x & 63;

    for (int dst = blockIdx.x * 4 + wave; dst < N; dst += gridDim.x * 4) {
        const int start = rowp[dst], end = rowp[dst + 1];
        const float adv = ad_[dst];
        float dsum = 0.0f, acc = 0.0f;
        for (int i0 = start; i0 < end; i0 += 64) {
            int cnt = min(64, end - i0);
            int i = i0 + lane;
            int s = 0;
            if (i < end) {
                int e = eid[i];
                s = (e < E) ? srcs[e] : (e - E);
                float t = as_[s] + adv;
                t = (t > 0.f) ? t : NEG_SLOPE * t;
                float ex = __expf(t);
                dsum += ex;
                s_alpha[wave][lane] = ex;
            }
            __builtin_amdgcn_wave_barrier();
#pragma unroll 4
            for (int k = 0; k < cnt; k++) {
                float a_k = s_alpha[wave][k];
                int   s_k = __shfl(s, k);
                acc += a_k * hfeat[(size_t)s_k * 64 + lane];
            }
            __builtin_amdgcn_wave_barrier();
        }
#pragma unroll
        for (int mk = 32; mk >= 1; mk >>= 1) dsum += __shfl_xor(dsum, mk);
        float g2val = acc / (dsum + EPS_A) + bias2[lane];   // g2[dst][lane]

        // ---- fusion MLP on the register-resident g2 row ----
        float hacc = sb1[lane];
#pragma unroll 8
        for (int k = 0; k < 64; k++) hacc += __shfl(g2val, k) * sW[k * 64 + lane];
        float tval = tt[(size_t)dst * 32 + (lane & 31)];
#pragma unroll 8
        for (int k = 0; k < 32; k++) hacc += __shfl(tval, k) * sW[(64 + k) * 64 + lane];
        hacc = fmaxf(hacc, 0.0f);
        float o0 = hacc * sW2[lane * 2 + 0];
        float o1 = hacc * sW2[lane * 2 + 1];
#pragma unroll
        for (int mk = 32; mk >= 1; mk >>= 1) {
            o0 += __shfl_xor(o0, mk);
            o1 += __shfl_xor(o1, mk);
        }
        if (lane == 0) {
            out[(size_t)dst * 2 + 0] = o0 + bf2[0];
            out[(size_t)dst * 2 + 1] = o1 + bf2[1];
        }
    }
}

extern "C" void kernel_launch(void* const* d_in, const int* in_sizes, int n_in,
                              void* d_out, int out_size, void* d_ws, size_t ws_size,
                              hipStream_t stream) {
    const float* x      = (const float*)d_in[0];
    const int*   eidx   = (const int*)d_in[1];
    const float* seq    = (const float*)d_in[2];
    const float* W1     = (const float*)d_in[3];
    const float* att_s1 = (const float*)d_in[4];
    const float* att_d1 = (const float*)d_in[5];
    const float* bias1  = (const float*)d_in[6];
    const float* W2     = (const float*)d_in[7];
    const float* att_s2 = (const float*)d_in[8];
    const float* att_d2 = (const float*)d_in[9];
    const float* bias2  = (const float*)d_in[10];
    const float* Wih    = (const float*)d_in[11];
    const float* Whh    = (const float*)d_in[12];
    const float* bih    = (const float*)d_in[13];
    const float* bhh    = (const float*)d_in[14];
    const float* Wf1    = (const float*)d_in[15];
    const float* bf1    = (const float*)d_in[16];
    const float* Wf2    = (const float*)d_in[17];
    const float* bf2    = (const float*)d_in[18];
    float* out = (float*)d_out;

    const int N  = in_sizes[0] / IN_F;   // 50000
    const int E  = in_sizes[1] / 2;      // 800000
    const int ET = E + N;
    const int* srcs = eidx;
    const int* dsts = eidx + E;

    // workspace layout
    float* fws = (float*)d_ws;
    size_t o = 0;
    float* h1  = fws + o; o += (size_t)N * 256;
    float* g1  = fws + o; o += (size_t)N * 256;
    float* as1 = fws + o; o += (size_t)N * 4;
    float* ad1 = fws + o; o += (size_t)N * 4;
    int* cnt    = (int*)(fws + o);
    int* rowp   = cnt + N;
    int* cursor = rowp + N + 1;
    int* eid    = cursor + N;
    int* bsum   = eid + ET;
    float* ttded = (float*)(bsum + 256);          // dedicated tt (N*32 floats)
    size_t need = ((char*)(ttded + (size_t)N * 32)) - (char*)d_ws;
    bool bigws = need <= ws_size;
    // bigws: tt dedicated -> LSTM can run concurrently with agg4 (which reads h1)
    // smallws: tt aliases h1+N*128 -> LSTM must run after agg4 (h1 dead then)
    float* tt = bigws ? ttded : (h1 + (size_t)N * 128);
    float* h2 = h1;                      // N*64 (h1 dead after layer-1 agg)
    float* as2 = as1; float* ad2 = ad1;

    const int nTiles = (N + 255) / 256;
    const int lstmBlocks = (N + 31) / 32;    // 1563
    const int aggBlocks  = (N + 3) / 4;      // 12500
    dim3 blk(256);

    // ---- CSR build ----
    hipMemsetAsync(cnt, 0, (size_t)N * sizeof(int), stream);
    hipMemsetAsync(cursor, 0, (size_t)N * sizeof(int), stream);
    count_deg<<<(ET + 255) / 256, blk, 0, stream>>>(dsts, E, ET, cnt);
    scan1<<<nTiles, blk, 0, stream>>>(cnt, rowp, bsum, N);
    scan2<<<1, blk, 0, stream>>>(bsum, nTiles);
    scan3<<<(N + 256) / 256, blk, 0, stream>>>(rowp, bsum, N, ET);
    scatter_edges<<<(ET + 255) / 256, blk, 0, stream>>>(dsts, E, ET, rowp, cursor, eid);

    // ---- GAT layer 1 GEMM + fused attention scores ----
    gemm64<128, 256, 4><<<dim3((N + 63) / 64, 4), blk, 0, stream>>>(
        x, W1, h1, N, att_s1, att_d1, as1, ad1);

    // ---- merged: layer-1 aggregation + LSTM (interleaved block mapping) ----
    if (bigws) {
        mega_agg4_lstm<<<lstmBlocks + aggBlocks, blk, 0, stream>>>(
            srcs, E, rowp, eid, as1, ad1, h1, bias1, g1, N,
            seq, Wih, Whh, bih, bhh, tt, lstmBlocks);
    } else {
        mega_agg4_lstm<<<aggBlocks, blk, 0, stream>>>(
            srcs, E, rowp, eid, as1, ad1, h1, bias1, g1, N,
            seq, Wih, Whh, bih, bhh, tt, 0);
        lstm_standalone<<<lstmBlocks, blk, 0, stream>>>(seq, Wih, Whh, bih, bhh, tt, N);
    }

    // ---- GAT layer 2 GEMM + fused attention scores ----
    gemm64<256, 64, 1><<<dim3((N + 63) / 64, 1), blk, 0, stream>>>(
        g1, W2, h2, N, att_s2, att_d2, as2, ad2);

    // ---- layer-2 aggregation + fusion MLP fused ----
    gat_agg1_fused<<<1536, blk, 0, stream>>>(srcs, E, rowp, eid, as2, ad2, h2,
                                             bias2, tt, Wf1, bf1, Wf2, bf2, out, N);
}